// Round 4
// baseline (392.026 us; speedup 1.0000x reference)
//
#include <hip/hip_runtime.h>
#include <stdint.h>

typedef short short8_t __attribute__((ext_vector_type(8)));
typedef unsigned short ushort2_t __attribute__((ext_vector_type(2)));
typedef float f32x4    __attribute__((ext_vector_type(4)));

__device__ __forceinline__ unsigned short f2bf(float f) {
  unsigned int u = __float_as_uint(f);
  u += 0x7FFFu + ((u >> 16) & 1u);          // round-to-nearest-even
  return (unsigned short)(u >> 16);
}

// async global->LDS, 16B per lane; LDS dest = wave-uniform base + lane*16
__device__ __forceinline__ void glld16(const void* src, char* lds) {
  __builtin_amdgcn_global_load_lds(
      (const __attribute__((address_space(1))) void*)src,
      (__attribute__((address_space(3))) void*)lds, 16, 0, 0);
}

// swizzled b128 LDS read: XOR bits 4-6 keyed on bits 7-9 (matches pre-swizzled source)
__device__ __forceinline__ short8_t lds_rd(const char* smem, int a) {
  int aa = a ^ (((a >> 7) & 7) << 4);
  return *(const short8_t*)(smem + aa);
}

// ---------- kernel 1: min/max of conv_weight ----------
__global__ __launch_bounds__(256) void minmax_kernel(const float* __restrict__ w,
                                                     float* __restrict__ mm) {
  int tid = threadIdx.x;
  float mn = 1e30f, mx = -1e30f;
  const float4* w4 = (const float4*)w;      // 9216 float4
  for (int i = tid; i < 9216; i += 256) {
    float4 v = w4[i];
    mn = fminf(mn, fminf(fminf(v.x, v.y), fminf(v.z, v.w)));
    mx = fmaxf(mx, fmaxf(fmaxf(v.x, v.y), fmaxf(v.z, v.w)));
  }
  for (int off = 32; off; off >>= 1) {
    mn = fminf(mn, __shfl_down(mn, off));
    mx = fmaxf(mx, __shfl_down(mx, off));
  }
  __shared__ float smn[4], smx[4];
  if ((tid & 63) == 0) { smn[tid >> 6] = mn; smx[tid >> 6] = mx; }
  __syncthreads();
  if (tid == 0) {
    mn = fminf(fminf(smn[0], smn[1]), fminf(smn[2], smn[3]));
    mx = fmaxf(fmaxf(smx[0], smx[1]), fmaxf(smx[2], smx[3]));
    mm[0] = mn; mm[1] = mx;
  }
}

// ---------- kernel 2: hash weights -> bf16 in MFMA fragment layout ----------
// Output layout: [tap][frag i=mt*2+ks][lane=g*16+m][8 ushorts], so conv loads are
// fully coalesced dwordx4 and land directly in each lane's A-fragment registers.
__global__ __launch_bounds__(256) void hashprep_kernel(const float* __restrict__ w,
                                                       const float* __restrict__ hv,
                                                       const float* __restrict__ mm,
                                                       unsigned short* __restrict__ w0,
                                                       unsigned short* __restrict__ w1) {
  int t = blockIdx.x * 256 + threadIdx.x;   // 0..36863, layout [co][ci][kh][kw]
  if (t >= 36864) return;
  float mn = mm[0], mx = mm[1];
  float width = (mx - mn) / 256.0f;
  float wv = w[t];
  int idx = min(max((int)floorf((wv - mn) / width), 0), 255);
  float hw = hv[idx];
  int co  = t / 576;
  int rem = t - co * 576;
  int ci  = rem / 9;
  int tap = rem - ci * 9;
  int mt = co >> 4, m = co & 15;
  int ks = ci >> 5, g = (ci & 31) >> 3, e = ci & 7;   // frag elem j <-> ci = ks*32+g*8+j
  int dst = ((tap * 8 + mt * 2 + ks) * 64 + g * 16 + m) * 8 + e;
  w0[dst] = f2bf(wv);
  w1[dst] = f2bf(hw);
}

// ---------- kernel 3: x (f32 NCHW) -> Xbf (bf16 [b][h][w' 0..129][ci]) via LDS transpose ----
// Coalesced float4 reads (lane sweeps w), LDS [c][w] stride 130 ushorts (coef 65 == 1 mod 32:
// phase-1 writes 2-way free, phase-2 reads 4-way), coalesced 16B output stores.
__global__ __launch_bounds__(256) void xprep_kernel(const float* __restrict__ x,
                                                    unsigned short* __restrict__ xbf) {
  __shared__ unsigned short T[64 * 130];
  int t  = threadIdx.x;
  int bh = blockIdx.x;                       // b*128 + h
  int b = bh >> 7, h = bh & 127;
  const f32x4* x4 = (const f32x4*)x;
  size_t xrow = (((size_t)(b * 64) * 128 + h) << 5);   // float4 idx at c=0
  #pragma unroll
  for (int k = 0; k < 8; ++k) {
    int j = k * 256 + t;                     // < 2048
    int c = j >> 5, w4 = j & 31;
    f32x4 v = x4[xrow + ((size_t)c << 12) + w4];       // c stride = 4096 float4
    ushort2_t lo, hi;
    lo[0] = f2bf(v[0]); lo[1] = f2bf(v[1]);
    hi[0] = f2bf(v[2]); hi[1] = f2bf(v[3]);
    *(ushort2_t*)&T[c * 130 + w4 * 4]     = lo;
    *(ushort2_t*)&T[c * 130 + w4 * 4 + 2] = hi;
  }
  __syncthreads();
  size_t rb = (size_t)bh * (130 * 64);       // ushort index of row base
  if (t < 16) {                              // zero halo columns w'=0 and w'=129
    short8_t z = {0, 0, 0, 0, 0, 0, 0, 0};
    int col = (t < 8) ? 0 : 129, ch = t & 7;
    *(short8_t*)(xbf + rb + col * 64 + ch * 8) = z;
  }
  #pragma unroll
  for (int k = 0; k < 4; ++k) {
    int q = k * 256 + t;                     // < 1024
    int w = q >> 3, o8 = (q & 7) * 8;
    short8_t v;
    #pragma unroll
    for (int j = 0; j < 8; ++j) v[j] = (short)T[(o8 + j) * 130 + w];
    *(short8_t*)(xbf + rb + (size_t)(w + 1) * 64 + o8) = v;
  }
}

// ---------- kernel 4: conv via 9 shifted 1x1 GEMMs, W in registers ----------
// 4 waves (256 thr), 2 blocks/CU (LDS 50688B). Block = 64co x 4h x 64w; wave = 1 h-row.
// X staged once via global_load_lds (pre-swizzled source); W loaded per-tap from the
// fragment-layout global buffer (coalesced, L2-resident). ONE barrier total.
#define XR 8448   // staged row: 66 cols * 128B

template<int NSETS>
__global__ __launch_bounds__(256, 2) void conv_kernel(
    const unsigned short* __restrict__ xbf,
    const char* __restrict__ zeropage,      // >= 8464 zeroed bytes
    const unsigned short* __restrict__ wf0,
    const unsigned short* __restrict__ wf1,
    const float* __restrict__ bias,
    float* __restrict__ out0,
    float* __restrict__ out1) {

  __shared__ char smem[6 * XR];

  int tid = threadIdx.x, lane = tid & 63, wv = tid >> 6;
  int m = lane & 15, g = lane >> 4;

  int bx0 = blockIdx.x;
  int bx  = (bx0 & 7) * 128 + (bx0 >> 3);   // bijective XCD-chunked swizzle (1024 % 8 == 0)
  int b = bx >> 6, rowblk = (bx >> 1) & 31, wblk = bx & 1;
  int h0 = rowblk * 4, W0 = wblk * 64;

  const unsigned short* wsrc[2] = {wf0, wf1};

  // preload W tap 0 into registers (overlaps X staging)
  short8_t aw[NSETS][8];
  #pragma unroll
  for (int s = 0; s < NSETS; ++s)
    #pragma unroll
    for (int i = 0; i < 8; ++i)
      aw[s][i] = *(const short8_t*)(wsrc[s] + i * 512 + lane * 8);

  // stage X: 6 rows (h0-1 .. h0+4) x 66 cols x 64c = 3168 16B chunks
  const char* xb = (const char*)xbf + (size_t)b * (130 * 128 * 128) + (size_t)W0 * 128;
  for (int batch = wv; batch < 50; batch += 4) {
    int q = batch * 64 + lane;
    if (q < 3168) {
      int r = q / 528;
      int o = (q - r * 528) << 4;
      int swz = o ^ (((q >> 3) & 7) << 4);
      int hin = h0 + r - 1;
      const char* src = ((unsigned)hin < 128u) ? (xb + (size_t)hin * 16640 + swz)
                                               : (zeropage + swz);
      glld16(src, smem + batch * 1024);
    }
  }

  f32x4 acc[NSETS][4][4];
  #pragma unroll
  for (int s = 0; s < NSETS; ++s)
    #pragma unroll
    for (int i = 0; i < 4; ++i)
      #pragma unroll
      for (int j = 0; j < 4; ++j) acc[s][i][j] = (f32x4){0.f, 0.f, 0.f, 0.f};

  int bcol[4];
  #pragma unroll
  for (int nf = 0; nf < 4; ++nf) bcol[nf] = ((nf * 16 + m) << 7) + (g << 4);

  __syncthreads();                          // X (and W tap0) resident

  #pragma unroll
  for (int t = 0; t < 9; ++t) {
    if (t) {
      #pragma unroll
      for (int s = 0; s < NSETS; ++s)
        #pragma unroll
        for (int i = 0; i < 8; ++i)
          aw[s][i] = *(const short8_t*)(wsrc[s] + t * 4096 + i * 512 + lane * 8);
    }
    int kh = t / 3, kw = t - kh * 3;
    int xtap = (wv + kh) * XR + (kw << 7);
    #pragma unroll
    for (int ks = 0; ks < 2; ++ks) {
      short8_t bf[4];
      #pragma unroll
      for (int nf = 0; nf < 4; ++nf) bf[nf] = lds_rd(smem, xtap + bcol[nf] + (ks << 6));
      #pragma unroll
      for (int s = 0; s < NSETS; ++s)
        #pragma unroll
        for (int mt = 0; mt < 4; ++mt)
          #pragma unroll
          for (int nf = 0; nf < 4; ++nf)
            acc[s][mt][nf] = __builtin_amdgcn_mfma_f32_16x16x32_bf16(
                aw[s][mt * 2 + ks], bf[nf], acc[s][mt][nf], 0, 0, 0);
    }
  }

  // epilogue: row = h0+wv, co = mt*16+g*4+r4, px = W0 + nf*16+m
  size_t ob = (size_t)b * 64 * 16384 + (size_t)(h0 + wv) * 128 + W0;
  #pragma unroll
  for (int s = 0; s < NSETS; ++s) {
    float* op = s ? out1 : out0;
    #pragma unroll
    for (int mt = 0; mt < 4; ++mt)
      #pragma unroll
      for (int r4 = 0; r4 < 4; ++r4) {
        int co = mt * 16 + g * 4 + r4;
        float bv = bias[co];
        #pragma unroll
        for (int nf = 0; nf < 4; ++nf)
          op[ob + (size_t)co * 16384 + nf * 16 + m] = acc[s][mt][nf][r4] + bv;
      }
  }
}

// ---------- launch ----------
extern "C" void kernel_launch(void* const* d_in, const int* in_sizes, int n_in,
                              void* d_out, int out_size, void* d_ws, size_t ws_size,
                              hipStream_t stream) {
  const float* x    = (const float*)d_in[0];
  const float* xh   = (const float*)d_in[1];
  const float* cw   = (const float*)d_in[2];
  const float* hv   = (const float*)d_in[3];
  const float* bias = (const float*)d_in[4];

  float* out      = (float*)d_out;
  float* hash_out = out + 16777216;
  float* out_hash = out + 33554432;

  char* ws = (char*)d_ws;
  float* mm            = (float*)ws;
  char* zeropage       = ws + 128;                        // 16640 B
  unsigned short* w0F  = (unsigned short*)(ws + 32768);   // [9][8][64][8] bf16 frag layout
  unsigned short* w1F  = (unsigned short*)(ws + 32768 + 73728);
  unsigned short* xbf  = (unsigned short*)(ws + 180224);  // [16][128][130][64] bf16

  hipMemsetAsync(zeropage, 0, 16640, stream);
  minmax_kernel<<<1, 256, 0, stream>>>(cw, mm);
  hashprep_kernel<<<144, 256, 0, stream>>>(cw, hv, mm, w0F, w1F);

  xprep_kernel<<<2048, 256, 0, stream>>>(x, xbf);
  conv_kernel<2><<<1024, 256, 0, stream>>>(xbf, zeropage, w0F, w1F, bias, out, hash_out);
  xprep_kernel<<<2048, 256, 0, stream>>>(xh, xbf);
  conv_kernel<1><<<1024, 256, 0, stream>>>(xbf, zeropage, w1F, w1F, bias, out_hash, out_hash);
}